// Round 1
// baseline (157.982 us; speedup 1.0000x reference)
//
#include <hip/hip_runtime.h>
#include <stdint.h>

// ---------------------------------------------------------------------------
// SlidingAttentionModule: B=2, S=2048, D=1024, H=16, hd=64, window +-8
//   qkv = x @ w_qkv^T + b_qkv          (bf16 MFMA GEMM, M=4096 N=3072 K=1024)
//   attn: per-query 17-key sliding window softmax (fp32, wave-per-query)
//   out = ctx @ w_out^T + b_out        (bf16 MFMA GEMM, M=4096 N=1024 K=1024)
// ---------------------------------------------------------------------------

typedef __bf16 bf16_t;
typedef bf16_t bf16x8 __attribute__((ext_vector_type(8)));
typedef unsigned short u16x8 __attribute__((ext_vector_type(8)));
typedef float f32x4 __attribute__((ext_vector_type(4)));

#define GLD16(g, l)                                                        \
  __builtin_amdgcn_global_load_lds(                                        \
      (const __attribute__((address_space(1))) void*)(g),                  \
      (__attribute__((address_space(3))) void*)(l), 16, 0, 0)

__device__ __forceinline__ unsigned short f2bf(float f) {
  unsigned int u = __float_as_uint(f);
  u += 0x7FFFu + ((u >> 16) & 1u);  // round-to-nearest-even
  return (unsigned short)(u >> 16);
}

// --- fp32 -> bf16 conversion, 4 elems/thread --------------------------------
__global__ void cvt_f32_bf16(const float* __restrict__ in,
                             unsigned short* __restrict__ out, int n4) {
  int i = blockIdx.x * blockDim.x + threadIdx.x;
  if (i >= n4) return;
  const float4 f = reinterpret_cast<const float4*>(in)[i];
  ushort4 o;
  o.x = f2bf(f.x); o.y = f2bf(f.y); o.z = f2bf(f.z); o.w = f2bf(f.w);
  reinterpret_cast<ushort4*>(out)[i] = o;
}

// --- bf16 GEMM: C[m,n] = sum_k A[m,k]*Bt[n,k] + bias[n] ---------------------
// m97 structure: 128x128 tile, BK=32, 4 waves (2x2), 4x4 16x16x32 frags/wave,
// global_load_lds width=16 staging, 2 barriers per K-step.
// EPI=0: plain fp32 write to Cp[m*N+n].
// EPI=1: scatter q/k/v into [B,H,S,hd] fp32 (n<1024:q, <2048:k, else v).
template <int EPI>
__global__ __launch_bounds__(256, 2) void gemm_bt(
    const unsigned short* __restrict__ A,   // [M,K] bf16 bits
    const unsigned short* __restrict__ Bt,  // [N,K] bf16 bits
    const float* __restrict__ bias,         // [N]
    float* __restrict__ Cq, float* __restrict__ Ck, float* __restrict__ Cv,
    float* __restrict__ Cp, int M, int N, int K) {
  __shared__ unsigned short sA[128 * 32];
  __shared__ unsigned short sB[128 * 32];

  const int tid = threadIdx.x;
  const int wave = tid >> 6;
  const int lane = tid & 63;
  const int m0 = blockIdx.x * 128;
  const int n0 = blockIdx.y * 128;
  const int wr = wave >> 1;  // 0..1 (row half of tile)
  const int wc = wave & 1;   // 0..1 (col half of tile)

  f32x4 acc[4][4] = {};

  // staging: thread t loads 16B = 8 bf16; row t/4, kchunk (t%4)*8
  const int srow = tid >> 2;
  const int scol = (tid & 3) << 3;
  const unsigned short* Ag0 = A + (size_t)(m0 + srow) * K + scol;
  const unsigned short* Ag1 = Ag0 + (size_t)64 * K;
  const unsigned short* Bg0 = Bt + (size_t)(n0 + srow) * K + scol;
  const unsigned short* Bg1 = Bg0 + (size_t)64 * K;
  unsigned short* sA0 = &sA[wave * 512];        // wave-uniform LDS bases
  unsigned short* sA1 = &sA[2048 + wave * 512];
  unsigned short* sB0 = &sB[wave * 512];
  unsigned short* sB1 = &sB[2048 + wave * 512];

  // fragment read indices (16x16x32: A row = lane&15, k = (lane>>4)*8 + j)
  const int ar = wr * 64 + (lane & 15);
  const int br = wc * 64 + (lane & 15);
  const int kc = (lane >> 4) << 3;

  for (int k0 = 0; k0 < K; k0 += 32) {
    __syncthreads();  // previous compute done before overwrite
    GLD16(Ag0 + k0, sA0);
    GLD16(Ag1 + k0, sA1);
    GLD16(Bg0 + k0, sB0);
    GLD16(Bg1 + k0, sB1);
    __syncthreads();  // implicit vmcnt(0) drain -> staging complete

    bf16x8 af[4], bfr[4];
#pragma unroll
    for (int f = 0; f < 4; ++f) {
      af[f] = __builtin_bit_cast(
          bf16x8, *reinterpret_cast<const u16x8*>(&sA[(ar + f * 16) * 32 + kc]));
      bfr[f] = __builtin_bit_cast(
          bf16x8, *reinterpret_cast<const u16x8*>(&sB[(br + f * 16) * 32 + kc]));
    }
#pragma unroll
    for (int i = 0; i < 4; ++i)
#pragma unroll
      for (int j = 0; j < 4; ++j)
        acc[i][j] =
            __builtin_amdgcn_mfma_f32_16x16x32_bf16(af[i], bfr[j], acc[i][j], 0, 0, 0);
  }

  // epilogue: C/D layout col = lane&15, row = (lane>>4)*4 + reg  [m89]
#pragma unroll
  for (int i = 0; i < 4; ++i) {
    const int row0 = m0 + wr * 64 + i * 16 + ((lane >> 4) << 2);
#pragma unroll
    for (int j = 0; j < 4; ++j) {
      const int col = n0 + wc * 64 + j * 16 + (lane & 15);
      const float bb = bias[col];
#pragma unroll
      for (int r = 0; r < 4; ++r) {
        const int m = row0 + r;
        const float val = acc[i][j][r] + bb;
        if (EPI == 0) {
          Cp[(size_t)m * N + col] = val;
        } else {
          const int b = m >> 11, s = m & 2047;
          const int which = col >> 10, nn = col & 1023;
          const int h = nn >> 6, d = nn & 63;
          float* dst = (which == 0) ? Cq : (which == 1) ? Ck : Cv;
          dst[(((size_t)(b * 16 + h)) * 2048 + s) * 64 + d] = val;
        }
      }
    }
  }
}

// --- sliding-window attention: one wave per query, lane = head-dim ----------
__global__ __launch_bounds__(256) void attn_sliding(
    const float* __restrict__ Q, const float* __restrict__ Kt,
    const float* __restrict__ V, unsigned short* __restrict__ ctx) {
  const int gw = (blockIdx.x * blockDim.x + threadIdx.x) >> 6;  // query id
  const int lane = threadIdx.x & 63;
  const int i = gw & 2047;   // seq position
  const int bh = gw >> 11;   // 0..31  (b*16 + h)

  const float* qp = Q + ((size_t)bh * 2048 + i) * 64;
  const float* kp = Kt + (size_t)bh * 2048 * 64;
  const float* vp = V + (size_t)bh * 2048 * 64;

  const float qd = qp[lane] * 0.125f;  // 1/sqrt(64)

  int lo = i - 8; lo = lo < 0 ? 0 : lo;
  int hi = i + 8; hi = hi > 2047 ? 2047 : hi;

  float m = -1e30f, lsum = 0.f, acc = 0.f;
  for (int j = lo; j <= hi; ++j) {
    float p = qd * kp[(size_t)j * 64 + lane];
#pragma unroll
    for (int off = 32; off; off >>= 1) p += __shfl_xor(p, off);
    const float mn = fmaxf(m, p);
    const float scl = __expf(m - mn);
    const float e = __expf(p - mn);
    acc = acc * scl + e * vp[(size_t)j * 64 + lane];
    lsum = lsum * scl + e;
    m = mn;
  }
  const float o = acc / lsum;
  const int b = bh >> 4, h = bh & 15;
  ctx[(((size_t)b * 2048 + i) * 1024) + h * 64 + lane] = f2bf(o);
}

// ---------------------------------------------------------------------------
extern "C" void kernel_launch(void* const* d_in, const int* in_sizes, int n_in,
                              void* d_out, int out_size, void* d_ws,
                              size_t ws_size, hipStream_t stream) {
  const float* x = (const float*)d_in[0];      // [2,2048,1024]
  // d_in[1] token_ids: unused by reference
  const float* w_qkv = (const float*)d_in[2];  // [3072,1024]
  const float* b_qkv = (const float*)d_in[3];  // [3072]
  const float* w_out = (const float*)d_in[4];  // [1024,1024]
  const float* b_out = (const float*)d_in[5];  // [1024]
  float* out = (float*)d_out;                  // [2,2048,1024] fp32

  char* ws = (char*)d_ws;
  unsigned short* xb    = (unsigned short*)(ws + 0);         // 8 MB
  unsigned short* wqkvb = (unsigned short*)(ws + 8388608);   // 6 MB
  unsigned short* woutb = (unsigned short*)(ws + 14680064);  // 2 MB
  float* Qf   = (float*)(ws + 16777216);                     // 16 MB [B,H,S,hd]
  float* Kf   = (float*)(ws + 33554432);                     // 16 MB
  float* Vf   = (float*)(ws + 50331648);                     // 16 MB
  unsigned short* ctxb = (unsigned short*)(ws + 67108864);   // 8 MB [B,S,D]

  // fp32 -> bf16 conversions (n/4 threads, 4 elems each)
  cvt_f32_bf16<<<(1048576 + 255) / 256, 256, 0, stream>>>(x, xb, 1048576);
  cvt_f32_bf16<<<(786432 + 255) / 256, 256, 0, stream>>>(w_qkv, wqkvb, 786432);
  cvt_f32_bf16<<<(262144 + 255) / 256, 256, 0, stream>>>(w_out, woutb, 262144);

  // QKV projection: M=4096, N=3072, K=1024 -> scatter to Q/K/V [B,H,S,hd]
  gemm_bt<1><<<dim3(32, 24), 256, 0, stream>>>(xb, wqkvb, b_qkv, Qf, Kf, Vf,
                                               nullptr, 4096, 3072, 1024);

  // sliding attention: 65536 queries, 1 wave each, 4 waves/block
  attn_sliding<<<16384, 256, 0, stream>>>(Qf, Kf, Vf, ctxb);

  // out projection: M=4096, N=1024, K=1024 -> fp32 d_out
  gemm_bt<0><<<dim3(32, 8), 256, 0, stream>>>(ctxb, woutb, b_out, nullptr,
                                              nullptr, nullptr, out, 4096,
                                              1024, 1024);
}

// Round 2
// 89.928 us; speedup vs baseline: 1.7568x; 1.7568x over previous
//
#include <hip/hip_runtime.h>
#include <stdint.h>

// ---------------------------------------------------------------------------
// SlidingAttentionModule: B=2, S=2048, D=1024, H=16, hd=64, window +-8
//   qkv = x @ w_qkv^T + b_qkv     (bf16 MFMA GEMM -> Q,K [bh,s,d], V^T [bh,d,s])
//   attn: MFMA-tiled 16-query x 32-key sliding window, no max-subtraction
//   out = ctx @ w_out^T + b_out   (bf16 MFMA GEMM, fp32 out)
// ---------------------------------------------------------------------------

typedef __bf16 bf16_t;
typedef bf16_t bf16x8 __attribute__((ext_vector_type(8)));
typedef unsigned short u16x8 __attribute__((ext_vector_type(8)));
typedef float f32x4 __attribute__((ext_vector_type(4)));

#define GLD16(g, l)                                                        \
  __builtin_amdgcn_global_load_lds(                                        \
      (const __attribute__((address_space(1))) void*)(g),                  \
      (__attribute__((address_space(3))) void*)(l), 16, 0, 0)

__device__ __forceinline__ unsigned short f2bf(float f) {
  unsigned int u = __float_as_uint(f);
  u += 0x7FFFu + ((u >> 16) & 1u);  // round-to-nearest-even
  return (unsigned short)(u >> 16);
}

__device__ __forceinline__ bf16x8 ld16(const unsigned short* p) {
  return __builtin_bit_cast(bf16x8, *reinterpret_cast<const u16x8*>(p));
}

// --- fp32 -> bf16 conversion, 4 elems/thread --------------------------------
__global__ void cvt_f32_bf16(const float* __restrict__ in,
                             unsigned short* __restrict__ out, int n4) {
  int i = blockIdx.x * blockDim.x + threadIdx.x;
  if (i >= n4) return;
  const float4 f = reinterpret_cast<const float4*>(in)[i];
  ushort4 o;
  o.x = f2bf(f.x); o.y = f2bf(f.y); o.z = f2bf(f.z); o.w = f2bf(f.w);
  reinterpret_cast<ushort4*>(out)[i] = o;
}

// --- bf16 GEMM: C[m,n] = sum_k A[m,k]*Bt[n,k] + bias[n] ---------------------
// m97 structure: 128x128 tile, BK=32, 4 waves (2x2), 4x4 16x16x32 frags/wave.
// EPI=0: plain fp32 write to Cp[m*N+n].
// EPI=1: scatter bf16 q/k into [bh,s,64], v into [bh,d,2048] (transposed).
template <int EPI>
__global__ __launch_bounds__(256, 2) void gemm_bt(
    const unsigned short* __restrict__ A,   // [M,K] bf16 bits
    const unsigned short* __restrict__ Bt,  // [N,K] bf16 bits
    const float* __restrict__ bias,         // [N]
    unsigned short* __restrict__ Cq, unsigned short* __restrict__ Ck,
    unsigned short* __restrict__ Cv, float* __restrict__ Cp, int M, int N,
    int K) {
  __shared__ unsigned short sA[128 * 32];
  __shared__ unsigned short sB[128 * 32];

  const int tid = threadIdx.x;
  const int wave = tid >> 6;
  const int lane = tid & 63;
  const int m0 = blockIdx.x * 128;
  const int n0 = blockIdx.y * 128;
  const int wr = wave >> 1;
  const int wc = wave & 1;

  f32x4 acc[4][4] = {};

  const int srow = tid >> 2;
  const int scol = (tid & 3) << 3;
  const unsigned short* Ag0 = A + (size_t)(m0 + srow) * K + scol;
  const unsigned short* Ag1 = Ag0 + (size_t)64 * K;
  const unsigned short* Bg0 = Bt + (size_t)(n0 + srow) * K + scol;
  const unsigned short* Bg1 = Bg0 + (size_t)64 * K;
  unsigned short* sA0 = &sA[wave * 512];
  unsigned short* sA1 = &sA[2048 + wave * 512];
  unsigned short* sB0 = &sB[wave * 512];
  unsigned short* sB1 = &sB[2048 + wave * 512];

  const int ar = wr * 64 + (lane & 15);
  const int br = wc * 64 + (lane & 15);
  const int kc = (lane >> 4) << 3;

  for (int k0 = 0; k0 < K; k0 += 32) {
    __syncthreads();
    GLD16(Ag0 + k0, sA0);
    GLD16(Ag1 + k0, sA1);
    GLD16(Bg0 + k0, sB0);
    GLD16(Bg1 + k0, sB1);
    __syncthreads();

    bf16x8 af[4], bfr[4];
#pragma unroll
    for (int f = 0; f < 4; ++f) {
      af[f] = ld16(&sA[(ar + f * 16) * 32 + kc]);
      bfr[f] = ld16(&sB[(br + f * 16) * 32 + kc]);
    }
#pragma unroll
    for (int i = 0; i < 4; ++i)
#pragma unroll
      for (int j = 0; j < 4; ++j)
        acc[i][j] =
            __builtin_amdgcn_mfma_f32_16x16x32_bf16(af[i], bfr[j], acc[i][j], 0, 0, 0);
  }

  // epilogue: C/D layout col = lane&15, row = (lane>>4)*4 + reg  [m89]
#pragma unroll
  for (int i = 0; i < 4; ++i) {
    const int row0 = m0 + wr * 64 + i * 16 + ((lane >> 4) << 2);
#pragma unroll
    for (int j = 0; j < 4; ++j) {
      const int col = n0 + wc * 64 + j * 16 + (lane & 15);
      const float bb = bias[col];
#pragma unroll
      for (int r = 0; r < 4; ++r) {
        const int m = row0 + r;
        const float val = acc[i][j][r] + bb;
        if (EPI == 0) {
          Cp[(size_t)m * N + col] = val;
        } else {
          const int b = m >> 11, s = m & 2047;
          const int which = col >> 10, nn = col & 1023;
          const int h = nn >> 6, d = nn & 63;
          const int bh = (b << 4) + h;
          const unsigned short vb = f2bf(val);
          if (which == 0)
            Cq[((size_t)(bh * 2048 + s)) * 64 + d] = vb;
          else if (which == 1)
            Ck[((size_t)(bh * 2048 + s)) * 64 + d] = vb;
          else
            Cv[((size_t)(bh * 64 + d)) * 2048 + s] = vb;
        }
      }
    }
  }
}

// --- MFMA sliding attention: 1 wave = 16 queries x 32-key window ------------
// Q,K: [bh, s, 64] bf16.  Vt: [bh, d, 2048] bf16.  ctx out: [b, s, 1024] bf16.
__global__ __launch_bounds__(256) void attn_mfma(
    const unsigned short* __restrict__ Qb, const unsigned short* __restrict__ Kb,
    const unsigned short* __restrict__ Vt, unsigned short* __restrict__ ctx) {
  __shared__ unsigned short P[4][16][40];  // per-wave P tile, padded stride 40
  const int wave = threadIdx.x >> 6;
  const int lane = threadIdx.x & 63;
  const int gw = (blockIdx.x << 2) + wave;
  const int bh = gw >> 7;           // 0..31
  const int i0 = (gw & 127) << 4;   // query tile start
  const int qr = lane & 15;
  const int kg = lane >> 4;         // 0..3
  const int kc = kg << 3;           // k-offset

  // Q A-fragments (row = query qr, k = dim)
  const size_t qbase = ((size_t)(bh * 2048 + i0 + qr)) * 64;
  const bf16x8 aq0 = ld16(Qb + qbase + kc);
  const bf16x8 aq1 = ld16(Qb + qbase + 32 + kc);

  // QK^T: 2 key-tiles x 2 k-steps. B-frag: row = key (lane&15), k = dim.
  f32x4 sc0 = {0.f, 0.f, 0.f, 0.f}, sc1 = {0.f, 0.f, 0.f, 0.f};
  {
    const int ka0 = i0 - 8 + qr;
    const int ka1 = ka0 + 16;
    const int kcl0 = min(max(ka0, 0), 2047);
    const int kcl1 = min(max(ka1, 0), 2047);
    const unsigned short* K0 = Kb + ((size_t)(bh * 2048 + kcl0)) * 64;
    const unsigned short* K1 = Kb + ((size_t)(bh * 2048 + kcl1)) * 64;
    sc0 = __builtin_amdgcn_mfma_f32_16x16x32_bf16(aq0, ld16(K0 + kc), sc0, 0, 0, 0);
    sc0 = __builtin_amdgcn_mfma_f32_16x16x32_bf16(aq1, ld16(K0 + 32 + kc), sc0, 0, 0, 0);
    sc1 = __builtin_amdgcn_mfma_f32_16x16x32_bf16(aq0, ld16(K1 + kc), sc1, 0, 0, 0);
    sc1 = __builtin_amdgcn_mfma_f32_16x16x32_bf16(aq1, ld16(K1 + 32 + kc), sc1, 0, 0, 0);
  }

  // mask + exp (no max-subtraction: |score| <= |q||k|/8, exp finite in fp32),
  // row-sum over 32 keys, stash P (bf16) in wave-private LDS.
  unsigned short* Pw = &P[wave][0][0];
  float lsum[4];
#pragma unroll
  for (int r = 0; r < 4; ++r) {
    const int q = (kg << 2) + r;   // score row = query
    const int key0 = qr, key1 = 16 + qr;
    const int ka0 = i0 - 8 + key0, ka1 = i0 - 8 + key1;
    const bool v0 = (q <= key0) && (key0 <= q + 16) && (ka0 >= 0) && (ka0 < 2048);
    const bool v1 = (q <= key1) && (key1 <= q + 16) && (ka1 >= 0) && (ka1 < 2048);
    const float e0 = v0 ? __expf(sc0[r] * 0.125f) : 0.f;
    const float e1 = v1 ? __expf(sc1[r] * 0.125f) : 0.f;
    Pw[q * 40 + key0] = f2bf(e0);
    Pw[q * 40 + key1] = f2bf(e1);
    float s = e0 + e1;
#pragma unroll
    for (int off = 1; off < 16; off <<= 1) s += __shfl_xor(s, off);
    lsum[r] = s;  // sum for query q, matches C-layout rows below
  }

  // P A-fragment: row = query qr, k = key
  const bf16x8 pa = ld16(&Pw[qr * 40 + kc]);

  // PV: 4 d-tiles, K=32 keys in one MFMA. B-frag from Vt: row = d, k = key.
  const int base_s = min(max(i0 - 8 + kc, 0), 2040);  // clamped chunks are fully masked
  f32x4 o[4];
  const f32x4 zero = {0.f, 0.f, 0.f, 0.f};
#pragma unroll
  for (int t2 = 0; t2 < 4; ++t2) {
    const unsigned short* Vr =
        Vt + ((size_t)(bh * 64 + t2 * 16 + qr)) * 2048 + base_s;
    o[t2] = __builtin_amdgcn_mfma_f32_16x16x32_bf16(pa, ld16(Vr), zero, 0, 0, 0);
  }

  // normalize + write ctx [b, s, 1024]
  const int b = bh >> 4, h = bh & 15;
  float rinv[4];
#pragma unroll
  for (int r = 0; r < 4; ++r) rinv[r] = 1.0f / lsum[r];
#pragma unroll
  for (int t2 = 0; t2 < 4; ++t2) {
#pragma unroll
    for (int r = 0; r < 4; ++r) {
      const int q = (kg << 2) + r;
      const int d = t2 * 16 + qr;
      ctx[((size_t)(b * 2048 + i0 + q)) * 1024 + (h << 6) + d] =
          f2bf(o[t2][r] * rinv[r]);
    }
  }
}

// ---------------------------------------------------------------------------
extern "C" void kernel_launch(void* const* d_in, const int* in_sizes, int n_in,
                              void* d_out, int out_size, void* d_ws,
                              size_t ws_size, hipStream_t stream) {
  const float* x = (const float*)d_in[0];      // [2,2048,1024]
  // d_in[1] token_ids: unused by reference
  const float* w_qkv = (const float*)d_in[2];  // [3072,1024]
  const float* b_qkv = (const float*)d_in[3];  // [3072]
  const float* w_out = (const float*)d_in[4];  // [1024,1024]
  const float* b_out = (const float*)d_in[5];  // [1024]
  float* out = (float*)d_out;                  // [2,2048,1024] fp32

  char* ws = (char*)d_ws;
  unsigned short* xb    = (unsigned short*)(ws + 0);         // 8 MB
  unsigned short* wqkvb = (unsigned short*)(ws + 8388608);   // 6 MB
  unsigned short* woutb = (unsigned short*)(ws + 14680064);  // 2 MB
  unsigned short* Qb    = (unsigned short*)(ws + 16777216);  // 8 MB [bh,s,64]
  unsigned short* Kb    = (unsigned short*)(ws + 25165824);  // 8 MB [bh,s,64]
  unsigned short* Vt    = (unsigned short*)(ws + 33554432);  // 8 MB [bh,d,2048]
  unsigned short* ctxb  = (unsigned short*)(ws + 41943040);  // 8 MB [b,s,1024]

  // fp32 -> bf16 conversions
  cvt_f32_bf16<<<(1048576 + 255) / 256, 256, 0, stream>>>(x, xb, 1048576);
  cvt_f32_bf16<<<(786432 + 255) / 256, 256, 0, stream>>>(w_qkv, wqkvb, 786432);
  cvt_f32_bf16<<<(262144 + 255) / 256, 256, 0, stream>>>(w_out, woutb, 262144);

  // QKV projection: M=4096, N=3072, K=1024 -> bf16 Q/K/Vt scatter
  gemm_bt<1><<<dim3(32, 24), 256, 0, stream>>>(xb, wqkvb, b_qkv, Qb, Kb, Vt,
                                               nullptr, 4096, 3072, 1024);

  // sliding attention: 4096 waves (16 queries each), 4 waves/block
  attn_mfma<<<1024, 256, 0, stream>>>(Qb, Kb, Vt, ctxb);

  // out projection: M=4096, N=1024, K=1024 -> fp32 d_out
  gemm_bt<0><<<dim3(32, 8), 256, 0, stream>>>(ctxb, woutb, b_out, nullptr,
                                              nullptr, nullptr, out, 4096,
                                              1024, 1024);
}